// Round 12
// baseline (4646.338 us; speedup 1.0000x reference)
//
#include <hip/hip_runtime.h>
#include <math.h>

typedef float v4 __attribute__((ext_vector_type(4)));
typedef unsigned long long u64;

static constexpr int B_ = 32;
static constexpr int S_ = 2048;
static constexpr int E_ = 512;
static constexpr int V_ = 32000;
static constexpr float EPS_ = 1e-6f;
static constexpr int NH_ = 8;     // blocks (column slices) per batch
static constexpr int CH_ = 64;    // columns per block

#define AG_ __HIP_MEMORY_SCOPE_AGENT
#define WG_ __HIP_MEMORY_SCOPE_WORKGROUP

// dot of broadcast(v: lane q holds element q) with per-lane w[64]:
// returns sum_q v[q]*w[q] at every lane. readlane = VALU broadcast, no LDS.
static __device__ __forceinline__ float rl_dot64(float v, const float* w) {
    float a0 = 0.f, a1 = 0.f, a2 = 0.f, a3 = 0.f;
    #pragma unroll
    for (int q = 0; q < 64; q += 4) {
        a0 = fmaf(__uint_as_float(__builtin_amdgcn_readlane(__float_as_uint(v), q + 0)), w[q + 0], a0);
        a1 = fmaf(__uint_as_float(__builtin_amdgcn_readlane(__float_as_uint(v), q + 1)), w[q + 1], a1);
        a2 = fmaf(__uint_as_float(__builtin_amdgcn_readlane(__float_as_uint(v), q + 2)), w[q + 2], a2);
        a3 = fmaf(__uint_as_float(__builtin_amdgcn_readlane(__float_as_uint(v), q + 3)), w[q + 3], a3);
    }
    return (a0 + a1) + (a2 + a3);
}

// ---------------------------------------------------------------------------
// K1: 8-blocks-per-batch scan, 256 blocks x 512 threads (8 waves).
// FUSED poll->partial structure, ZERO barriers in the loop:
//   wave j holds A[64j..64j+63][c0..c0+63] in w[64] VGPRs AND polls slice j
//   (its polled lane values ARE the rows it needs). On discovery: partial
//   matvec via readlane broadcast (no LDS staging, no shfl reduce - each
//   lane's acc IS its column partial), one part write, one counter bump.
//   Wave h (owner): spins cntM, sums 8 partials + XB partials, spins cntS,
//   sums 8 (S,Q) pairs (fixed order -> replica-identical stats), finalizes
//   zmid via the R9 algebra (zmid' = inv*(M - mu*G) + XB + b), publishes.
//   Wave h's own-slice contribution is computed from its just-finalized
//   zmid (registers) right after publish.
// Cross-wave deps: two monotone LDS counters (acquire/release + lgkmcnt).
// Parity-2 buffers; all shared writes are POST-poll (or intra-wave), which
// the parity-ring induction proves race-free. Exchange protocol: proven
// per-element tagged u64 relaxed agent atomics, memset replay guard.
// Deadlock-free: round-0 publish is unconditional; publish at round k
// depends only on local counters fed by polls of round k-1; max inter-block
// skew is one publish (opposite parity slot).
// ---------------------------------------------------------------------------
__global__ __launch_bounds__(512) void scanrl(
    const int* __restrict__ seq,     // (B,S)
    const float* __restrict__ emb,   // (V,E)
    const float* __restrict__ Wdec,  // (E,E) row-major
    const float* __restrict__ bdec,  // (E)
    const float* __restrict__ gamma, // (E)
    const float* __restrict__ beta,  // (E)
    float* __restrict__ zout,        // (B,E)
    u64* __restrict__ zpub)          // values (B,2,E) tagged exchange
{
    __shared__ float part[2][NH_][CH_];   // M partials, parity
    __shared__ float xpart[2][NH_][CH_];  // XB partials, parity
    __shared__ float sst[2][NH_][2];      // (S,Q) partials, parity
    __shared__ float zraw[E_];            // final-state values (epilogue)
    __shared__ unsigned cntM, cntS;       // monotone gather counters
    __shared__ int seq_l[S_];

    const int bid  = blockIdx.x;
    const int b    = bid & 31;
    const int h    = bid >> 5;
    const int c0   = h * CH_;
    const int tid  = threadIdx.x;
    const int wv   = tid >> 6;
    const int lane = tid & 63;
    const int r0   = wv * CH_;   // this wave's row block == its polled slice

    // --- A = I+W: w[q] = A[r0+q][c0+lane], q=0..63 (asm-pinned VGPRs) ---
    float w[64];
    {
        const float* wp = Wdec + (size_t)r0 * E_ + c0 + lane;
        #pragma unroll
        for (int q = 0; q < 64; ++q) {
            float t;
            asm volatile("global_load_dword %0, %1, off\n\ts_waitcnt vmcnt(0)"
                         : "=v"(t) : "v"(wp + (size_t)q * E_));
            w[q] = t;
        }
        #pragma unroll
        for (int q = 0; q < 64; ++q)
            if (r0 + q == c0 + lane) w[q] += 1.f;
    }

    const int* seqb = seq + (size_t)b * S_;
    for (int i = tid; i < S_; i += 512) seq_l[i] = seqb[i];

    const float sqrtE = sqrtf(512.f);
    const float gl = gamma[tid];       // gamma at my element (row r0+lane)
    const float bt = beta[tid];
    const float bd = bdec[c0 + lane];  // used by wave h only
    u64* zpb = zpub + (size_t)b * 2 * E_;

    if (tid == 0) { cntM = 0u; cntS = 0u; }
    __syncthreads();                         // seq_l + counters ready

    // prologue: G partials (gamma-weighted col sums of A) + XB^0 (x0, no beta)
    const float x0 = emb[(size_t)seq_l[0] * E_ + tid] * sqrtE;
    part[0][wv][lane]  = rl_dot64(gl, w);
    xpart[0][wv][lane] = rl_dot64(x0, w);
    __syncthreads();
    float G = 0.f;
    if (wv == h) {
        #pragma unroll
        for (int j = 0; j < NH_; ++j) G += part[0][j][lane];
    }
    float xv = fmaf(emb[(size_t)seq_l[1] * E_ + tid], sqrtE, bt);  // x1+beta
    __syncthreads();                 // G consumed; part[0] free for iter 0

    if (wv == h) {
        // =========== OWNER WAVE: finalize + publish, rounds k=0..S-1 =======
        float zlast = 0.f;
        for (int k = 0; k < S_; ++k) {
            const int kk = (k + 2 < S_) ? k + 2 : S_ - 1;
            const float ev = emb[(size_t)seq_l[kk] * E_ + tid];  // x_{k+2}

            float Mr = 0.f, mu = 0.f, inv = 0.f;
            if (k) {
                const int gp = (k - 1) & 1;
                while (__hip_atomic_load(&cntM, __ATOMIC_ACQUIRE, WG_)
                       < 8u * (unsigned)k) {}
                #pragma unroll
                for (int j = 0; j < NH_; ++j) Mr += part[gp][j][lane];
                while (__hip_atomic_load(&cntS, __ATOMIC_ACQUIRE, WG_)
                       < 8u * (unsigned)k) {}
                float St = 0.f, Qt = 0.f;
                #pragma unroll
                for (int j = 0; j < NH_; ++j) {
                    St += sst[gp][j][0]; Qt += sst[gp][j][1];
                }
                mu = St * (1.f / E_);
                const float var = (Qt - St * mu) * (1.f / (E_ - 1));
                inv = 1.f / (sqrtf(var) + EPS_);
            }
            const int xp = k & 1;
            float Xr = 0.f;
            #pragma unroll
            for (int j = 0; j < NH_; ++j) Xr += xpart[xp][j][lane];

            const float zmid = inv * (Mr - mu * G) + Xr + bd;
            union { float f; unsigned u; } cv; cv.f = zmid;
            __hip_atomic_store(&zpb[((k + 1) & 1) * E_ + c0 + lane],
                               ((u64)(unsigned)(k + 1) << 32) | cv.u,
                               __ATOMIC_RELAXED, AG_);

            // self-contribution to round k+1 (slice h, parity k&1)
            part[k & 1][h][lane]  = rl_dot64(gl * zmid, w);
            xpart[(k + 1) & 1][h][lane] = rl_dot64(xv, w);
            asm volatile("s_waitcnt lgkmcnt(0)" ::: "memory");
            if (lane == 0)
                __hip_atomic_fetch_add(&cntM, 1u, __ATOMIC_RELEASE, WG_);
            float s = zmid, q2 = zmid * zmid;
            #pragma unroll
            for (int m = 1; m < 64; m <<= 1) {
                s += __shfl_xor(s, m); q2 += __shfl_xor(q2, m);
            }
            if (lane == 0) { sst[k & 1][h][0] = s; sst[k & 1][h][1] = q2; }
            asm volatile("s_waitcnt lgkmcnt(0)" ::: "memory");
            if (lane == 0)
                __hip_atomic_fetch_add(&cntS, 1u, __ATOMIC_RELEASE, WG_);

            xv = fmaf(ev, sqrtE, bt);       // rotate x prefetch
            zlast = zmid;
        }
        zraw[c0 + lane] = zlast;
    } else {
        // =========== POLLER WAVES: gather + fused partial, i=0..S-1 ========
        for (int i = 0; i < S_; ++i) {
            const int kk = (i + 2 < S_) ? i + 2 : S_ - 1;
            const float ev = emb[(size_t)seq_l[kk] * E_ + tid];  // x_{i+2}
            const float xa = rl_dot64(xv, w);   // XB_{i+1} partial (RT shadow)

            // poll slice wv of zmid_i (tag i+1), 2-deep pipelined
            const unsigned tag = (unsigned)(i + 1);
            const u64* ap = &zpb[((i + 1) & 1) * E_ + r0 + lane];
            u64 s0 = __hip_atomic_load(ap, __ATOMIC_RELAXED, AG_);
            u64 s1 = __hip_atomic_load(ap, __ATOMIC_RELAXED, AG_);
            float val = 0.f; bool done = false;
            for (;;) {
                if (!done && (unsigned)(s0 >> 32) == tag) {
                    val = __uint_as_float((unsigned)s0); done = true;
                }
                if (__all(done)) break;
                s0 = __hip_atomic_load(ap, __ATOMIC_RELAXED, AG_);
                if (!done && (unsigned)(s1 >> 32) == tag) {
                    val = __uint_as_float((unsigned)s1); done = true;
                }
                if (__all(done)) break;
                s1 = __hip_atomic_load(ap, __ATOMIC_RELAXED, AG_);
            }

            // post-poll: parity buffers provably free (ring induction)
            xpart[(i + 1) & 1][wv][lane] = xa;
            part[i & 1][wv][lane] = rl_dot64(gl * val, w);
            asm volatile("s_waitcnt lgkmcnt(0)" ::: "memory");
            if (lane == 0)
                __hip_atomic_fetch_add(&cntM, 1u, __ATOMIC_RELEASE, WG_);
            float s = val, q2 = val * val;
            #pragma unroll
            for (int m = 1; m < 64; m <<= 1) {
                s += __shfl_xor(s, m); q2 += __shfl_xor(q2, m);
            }
            if (lane == 0) { sst[i & 1][wv][0] = s; sst[i & 1][wv][1] = q2; }
            asm volatile("s_waitcnt lgkmcnt(0)" ::: "memory");
            if (lane == 0)
                __hip_atomic_fetch_add(&cntS, 1u, __ATOMIC_RELEASE, WG_);

            if (i == S_ - 1) zraw[r0 + lane] = val;
            xv = fmaf(ev, sqrtE, bt);       // rotate x prefetch
        }
    }

    // --- epilogue: LN(zmid_{S-1}); only batch-replica h==0 writes ---
    while (__hip_atomic_load(&cntS, __ATOMIC_ACQUIRE, WG_)
           < 8u * (unsigned)S_) {}
    if (h == 0) {
        const int gp = (S_ - 1) & 1;
        float St = 0.f, Qt = 0.f;
        #pragma unroll
        for (int j = 0; j < NH_; ++j) { St += sst[gp][j][0]; Qt += sst[gp][j][1]; }
        const float mu  = St * (1.f / E_);
        const float var = (Qt - St * mu) * (1.f / (E_ - 1));
        const float inv = 1.f / (sqrtf(var) + EPS_);
        zout[(size_t)b * E_ + tid] = gl * (zraw[tid] - mu) * inv + bt;
    }
}

// ---------------------------------------------------------------------------
// K2: y = z @ W_voc + b_voc. 250 blocks x 512 threads; each thread owns one
// vocab column for 8 batches (bg group). z reads are thread-uniform ->
// scalar-cache loads; W_voc streamed once (same cols across bg reuse L1).
// ---------------------------------------------------------------------------
__global__ __launch_bounds__(512) void logits_k(
    const float* __restrict__ zfin,  // (B,E)
    const float* __restrict__ Wvoc,  // (E,V)
    const float* __restrict__ bvoc,  // (V)
    float* __restrict__ y)           // (B,V)
{
    const int tid = threadIdx.x;
    const int col = blockIdx.x * 128 + (tid & 127);
    const int bg  = (tid >> 7) * 8;           // 0,8,16,24

    float acc[8] = {0.f, 0.f, 0.f, 0.f, 0.f, 0.f, 0.f, 0.f};
    const float* wp = Wvoc + col;
    const float* zp = zfin + (size_t)bg * E_;

    for (int k = 0; k < E_; k += 4) {
        const float w0 = wp[(size_t)(k + 0) * V_];
        const float w1 = wp[(size_t)(k + 1) * V_];
        const float w2 = wp[(size_t)(k + 2) * V_];
        const float w3 = wp[(size_t)(k + 3) * V_];
        #pragma unroll
        for (int g = 0; g < 8; ++g) {
            acc[g] = fmaf(zp[g * E_ + k + 0], w0, acc[g]);
            acc[g] = fmaf(zp[g * E_ + k + 1], w1, acc[g]);
            acc[g] = fmaf(zp[g * E_ + k + 2], w2, acc[g]);
            acc[g] = fmaf(zp[g * E_ + k + 3], w3, acc[g]);
        }
    }
    const float bv = bvoc[col];
    #pragma unroll
    for (int g = 0; g < 8; ++g)
        y[(size_t)(bg + g) * V_ + col] = acc[g] + bv;
}

// ---------------------------------------------------------------------------
// K3: per-batch log-sum-exp (bias already folded into y)
// ---------------------------------------------------------------------------
__global__ __launch_bounds__(1024) void lse_k(
    const float* __restrict__ y, float* __restrict__ corr)
{
    __shared__ float redm[16], redl[16];
    const int b = blockIdx.x;
    const int tid = threadIdx.x;
    const float* row = y + (size_t)b * V_;

    float m = -3.0e38f, l = 0.f;
    for (int v = tid; v < V_; v += 1024) {
        const float x = row[v];
        const float nm = fmaxf(m, x);
        l = l * __expf(m - nm) + __expf(x - nm);
        m = nm;
    }
    #pragma unroll
    for (int off = 32; off > 0; off >>= 1) {
        const float om = __shfl_down(m, off);
        const float ol = __shfl_down(l, off);
        const float nm = fmaxf(m, om);
        l = l * __expf(m - nm) + ol * __expf(om - nm);
        m = nm;
    }
    const int lane = tid & 63, wvv = tid >> 6;
    if (lane == 0) { redm[wvv] = m; redl[wvv] = l; }
    __syncthreads();
    if (tid == 0) {
        float M = redm[0], L = redl[0];
        for (int k = 1; k < 16; ++k) {
            const float nm = fmaxf(M, redm[k]);
            L = L * __expf(M - nm) + redl[k] * __expf(redm[k] - nm);
            M = nm;
        }
        corr[b] = M + logf(L);
    }
}

// ---------------------------------------------------------------------------
// K4: y -= corr[b]
// ---------------------------------------------------------------------------
__global__ __launch_bounds__(256) void fix_k(
    float* __restrict__ y, const float* __restrict__ corr)
{
    const int idx = blockIdx.x * 256 + threadIdx.x;   // float4 index
    const size_t o = (size_t)idx * 4;
    const int b = (int)(o / V_);
    const float cr = corr[b];
    v4 v = *(v4*)(y + o);
    v = v - cr;
    *(v4*)(y + o) = v;
}

// ---------------------------------------------------------------------------
extern "C" void kernel_launch(void* const* d_in, const int* in_sizes, int n_in,
                              void* d_out, int out_size, void* d_ws, size_t ws_size,
                              hipStream_t stream)
{
    (void)in_sizes; (void)n_in; (void)out_size; (void)ws_size;
    // 0=hidden_state (unused), 1=output_sequence, 2=emb_out, 3=W_dec,
    // 4=b_dec, 5=gamma, 6=beta, 7=W_voc, 8=b_voc
    const int*   seq  = (const int*)  d_in[1];
    const float* emb  = (const float*)d_in[2];
    const float* Wdec = (const float*)d_in[3];
    const float* bdec = (const float*)d_in[4];
    const float* gam  = (const float*)d_in[5];
    const float* bet  = (const float*)d_in[6];
    const float* Wvoc = (const float*)d_in[7];
    const float* bvoc = (const float*)d_in[8];

    float* out  = (float*)d_out;
    float* zout = out;            // B*E floats
    float* y    = out + B_ * E_;  // B*V floats

    // workspace: values (B*2*E u64) + corr
    const size_t exch_u64 = (size_t)B_ * 2 * E_;
    u64*   zpub = (u64*)d_ws;
    float* corr = (float*)((char*)d_ws + exch_u64 * sizeof(u64)); // B floats

    // tags must not alias a previous replay — zero the exchange buf
    hipMemsetAsync(zpub, 0, exch_u64 * sizeof(u64), stream);

    hipLaunchKernelGGL(scanrl, dim3(B_ * NH_), dim3(512), 0, stream,
                       seq, emb, Wdec, bdec, gam, bet, zout, zpub);
    hipLaunchKernelGGL(logits_k, dim3(V_ / 128), dim3(512), 0, stream,
                       zout, Wvoc, bvoc, y);
    hipLaunchKernelGGL(lse_k, dim3(B_), dim3(1024), 0, stream, y, corr);
    hipLaunchKernelGGL(fix_k, dim3(1000), dim3(256), 0, stream, y, corr);
}